// Round 14
// baseline (1236.621 us; speedup 1.0000x reference)
//
#include <hip/hip_runtime.h>

// Social-LSTM on MI355X. fp32 I/O. 26 launches.
// Per frame: k_pool (1000 blk, R9 ILP-4 ballot-gather) -> k_glU (512 blk:
//   blocks 0-255 tiled gates-GEMM+LSTM (R9 k_gl), release ctr[t];
//   blocks 256-511 spin-acquire then tiled U'-GEMM + out-proj (R9 k_U)).
// All compute bodies verbatim from R9 (PASS, absmax 3.051758e-05).

#define TT    12
#define NN    1000
#define RNNW  128
#define OUTD  5
#define GROW  16000
#define UCW   1024
#define NCHK  63

__device__ __forceinline__ float sigmf(float x) { return 1.f / (1.f + __expf(-x)); }

// ---- prep: WsT (k-major W_soc), WcT (k-major, j2=r*4+gate permuted),
// bsum[j2], h/c init, ctr zero (R9 verified + ctr) -------------------------
__global__ void k_prep(const float* __restrict__ h0, const float* __restrict__ c0,
                       const float* __restrict__ W_soc,
                       const float* __restrict__ W_ih, const float* __restrict__ W_hh,
                       const float* __restrict__ b_ih, const float* __restrict__ b_hh,
                       float* __restrict__ h, float* __restrict__ c,
                       float* __restrict__ WsT, float* __restrict__ WcT,
                       float* __restrict__ bsum, unsigned int* __restrict__ ctr) {
    int i = blockIdx.x * 256 + threadIdx.x;
    if (i < 131072) {                       // WsT[gk][e] = W_soc[e][gk]
        int e = i >> 11, gk = i & 2047;
        WsT[gk * 64 + e] = W_soc[i];
    } else if (i < 196608) {                // W_ih [512][128] -> WcT[k][j2]
        int i2 = i - 131072;
        int j = i2 >> 7, k = i2 & 127;
        int j2 = (j & 127) * 4 + (j >> 7);
        WcT[k * 512 + j2] = W_ih[i2];
    } else if (i < 262144) {                // W_hh -> WcT[128+k][j2]
        int i3 = i - 196608;
        int j = i3 >> 7, k = i3 & 127;
        int j2 = (j & 127) * 4 + (j >> 7);
        WcT[(128 + k) * 512 + j2] = W_hh[i3];
    } else if (i < 262656) {                // bsum[j2]
        int j = i - 262144;
        int j2 = (j & 127) * 4 + (j >> 7);
        bsum[j2] = b_ih[j] + b_hh[j];
    } else if (i < 390656) {
        int i4 = i - 262656; h[i4] = h0[i4];
    } else if (i < 518656) {
        int i5 = i - 390656; c[i5] = c0[i5];
    } else if (i < 518656 + TT) {
        ctr[i - 518656] = 0u;               // frame sync counters
    }
}

// ---- k_U: standalone U for frame 0 (R9 verified, t=-1 path) --------------
__global__ __launch_bounds__(256) void k_U(const float* __restrict__ h,
                                           const float* __restrict__ WsT,
                                           float* __restrict__ U) {
    __shared__ float sAT[RNNW][64];
    __shared__ float sBT[RNNW][64];
    const int tid = threadIdx.x;
    const int p0 = blockIdx.x * 64;
    const int g  = blockIdx.y;
    {
        int pp = tid >> 2, kq = (tid & 3) * 4;
        int p = p0 + pp;
        #pragma unroll
        for (int pass = 0; pass < 8; ++pass) {
            int k0 = pass * 16 + kq;
            float4 v = {0.f, 0.f, 0.f, 0.f};
            if (p < NN) v = *(const float4*)(h + (size_t)p * RNNW + k0);
            sAT[k0 + 0][pp] = v.x; sAT[k0 + 1][pp] = v.y;
            sAT[k0 + 2][pp] = v.z; sAT[k0 + 3][pp] = v.w;
        }
    }
    {
        #pragma unroll
        for (int pass = 0; pass < 8; ++pass) {
            int f = pass * 256 + tid;
            int k = f >> 4, e4 = (f & 15) * 4;
            float4 v = *(const float4*)(WsT + (size_t)(g * 128 + k) * 64 + e4);
            *(float4*)(&sBT[k][e4]) = v;
        }
    }
    __syncthreads();
    const int tx = tid & 15, ty = tid >> 4;
    float acc[4][4];
    #pragma unroll
    for (int i = 0; i < 4; i++)
        #pragma unroll
        for (int j = 0; j < 4; j++) acc[i][j] = 0.f;
    #pragma unroll 4
    for (int k = 0; k < RNNW; ++k) {
        float4 a4 = *(const float4*)(&sAT[k][ty * 4]);
        float4 b4 = *(const float4*)(&sBT[k][tx * 4]);
        const float av[4] = {a4.x, a4.y, a4.z, a4.w};
        const float bv[4] = {b4.x, b4.y, b4.z, b4.w};
        #pragma unroll
        for (int i = 0; i < 4; i++)
            #pragma unroll
            for (int j = 0; j < 4; j++) acc[i][j] += av[i] * bv[j];
    }
    #pragma unroll
    for (int i = 0; i < 4; i++) {
        int p = p0 + ty * 4 + i;
        if (p < NN) {
            float4 v = {acc[i][0], acc[i][1], acc[i][2], acc[i][3]};
            *(float4*)(U + (size_t)p * UCW + g * 64 + tx * 4) = v;
        }
    }
}

// ---- pool: 1000 blocks x 512 thr, ILP-4 gather (R9 verified) -------------
__global__ __launch_bounds__(512) void k_pool(const unsigned int* __restrict__ grd,
                                              const float* __restrict__ x_in,
                                              const float* __restrict__ U,
                                              const float* __restrict__ W_in,
                                              const float* __restrict__ b_in,
                                              const float* __restrict__ b_soc,
                                              float* __restrict__ A, int t) {
    const int n = blockIdx.x;
    const int tid = threadIdx.x;
    const int lane = tid & 63, wv = tid >> 6;
    const unsigned int* gp = grd + ((size_t)t * NN + n) * (size_t)GROW;
    float ac0 = 0.f, ac1 = 0.f, ac2 = 0.f, ac3 = 0.f;
    for (int it = 0; it < 8; ++it) {
        int cc = it * 8 + wv;
        if (cc >= NCHK) break;
        int f0 = cc * 256 + lane * 4;
        uint4 v = {0u, 0u, 0u, 0u};
        if (f0 < GROW) v = *(const uint4*)(gp + f0);
        unsigned long long m0 = __ballot(v.x != 0u);
        unsigned long long m1 = __ballot(v.y != 0u);
        unsigned long long m2 = __ballot(v.z != 0u);
        unsigned long long m3 = __ballot(v.w != 0u);
        const int base = cc * 256;
        while (m0 | m1 | m2 | m3) {
            float u0 = 0.f, u1 = 0.f, u2 = 0.f, u3 = 0.f;
            if (m0) { int b = __builtin_ctzll(m0); m0 &= m0 - 1;
                      int f = base + b * 4 + 0;
                      u0 = U[(size_t)(f >> 4) * UCW + (f & 15) * 64 + lane]; }
            if (m1) { int b = __builtin_ctzll(m1); m1 &= m1 - 1;
                      int f = base + b * 4 + 1;
                      u1 = U[(size_t)(f >> 4) * UCW + (f & 15) * 64 + lane]; }
            if (m2) { int b = __builtin_ctzll(m2); m2 &= m2 - 1;
                      int f = base + b * 4 + 2;
                      u2 = U[(size_t)(f >> 4) * UCW + (f & 15) * 64 + lane]; }
            if (m3) { int b = __builtin_ctzll(m3); m3 &= m3 - 1;
                      int f = base + b * 4 + 3;
                      u3 = U[(size_t)(f >> 4) * UCW + (f & 15) * 64 + lane]; }
            ac0 += u0; ac1 += u1; ac2 += u2; ac3 += u3;
        }
    }
    __shared__ float sAcc[8][64];
    sAcc[wv][lane] = (ac0 + ac1) + (ac2 + ac3);
    __syncthreads();
    if (tid < 64) {
        float s = 0.f;
        #pragma unroll
        for (int w = 0; w < 8; w++) s += sAcc[w][tid];
        float te = fmaxf(s + b_soc[tid], 0.f);
        float x0 = x_in[((size_t)t * NN + n) * 2 + 0];
        float x1 = x_in[((size_t)t * NN + n) * 2 + 1];
        float ie = fmaxf(W_in[tid * 2 + 0] * x0 + W_in[tid * 2 + 1] * x1 + b_in[tid], 0.f);
        A[(size_t)n * RNNW + tid]      = ie;
        A[(size_t)n * RNNW + 64 + tid] = te;
    }
}

// ---- k_glU: gl (blocks 0-255) + soft barrier + U'/out-proj (256-511) -----
__global__ __launch_bounds__(256) void k_glU(const float* __restrict__ A,
                                             const float* __restrict__ hin,
                                             float* __restrict__ hout,
                                             float* __restrict__ c,
                                             const float* __restrict__ WcT,
                                             const float* __restrict__ bsum,
                                             const float* __restrict__ WsT,
                                             const float* __restrict__ W_out,
                                             const float* __restrict__ b_out,
                                             float* __restrict__ U,
                                             float* __restrict__ out,
                                             unsigned int* __restrict__ ctr, int t) {
    __shared__ float smem[16384];   // 64 KB -> 2 blocks/CU, all 512 resident
    const int tid = threadIdx.x;
    const int bid = blockIdx.x;
    if (bid < 256) {
        // ================= gl: gates GEMM + in-register LSTM (R9) =========
        float* sAT = smem;          // [128][32]
        float* sBT = smem + 4096;   // [128][64]
        const int n0 = (bid & 31) * 32;
        const int j0 = (bid >> 5) * 64;
        const int tx = tid & 15, ty = tid >> 4;
        float acc[2][4];
        #pragma unroll
        for (int i = 0; i < 2; i++)
            #pragma unroll
            for (int j = 0; j < 4; j++) acc[i][j] = 0.f;
        for (int kc = 0; kc < 2; ++kc) {
            __syncthreads();
            {
                int nn = tid >> 3, kq = (tid & 7) * 4;
                int n = n0 + nn;
                const float* src = kc ? (hin + (size_t)n * RNNW) : (A + (size_t)n * RNNW);
                #pragma unroll
                for (int pass = 0; pass < 4; ++pass) {
                    int k0 = pass * 32 + kq;
                    float4 v = {0.f, 0.f, 0.f, 0.f};
                    if (n < NN) v = *(const float4*)(src + k0);
                    sAT[(k0 + 0) * 32 + nn] = v.x; sAT[(k0 + 1) * 32 + nn] = v.y;
                    sAT[(k0 + 2) * 32 + nn] = v.z; sAT[(k0 + 3) * 32 + nn] = v.w;
                }
            }
            {
                #pragma unroll
                for (int pass = 0; pass < 8; ++pass) {
                    int f = pass * 256 + tid;
                    int k = f >> 4, e4 = (f & 15) * 4;
                    float4 v = *(const float4*)(WcT + (size_t)(kc * 128 + k) * 512 + j0 + e4);
                    *(float4*)(&sBT[k * 64 + e4]) = v;
                }
            }
            __syncthreads();
            #pragma unroll 4
            for (int k = 0; k < 128; ++k) {
                float2 a2 = *(const float2*)(&sAT[k * 32 + ty * 2]);
                float4 b4 = *(const float4*)(&sBT[k * 64 + tx * 4]);
                const float av[2] = {a2.x, a2.y};
                const float bv[4] = {b4.x, b4.y, b4.z, b4.w};
                #pragma unroll
                for (int i = 0; i < 2; i++)
                    #pragma unroll
                    for (int j = 0; j < 4; j++) acc[i][j] += av[i] * bv[j];
            }
        }
        float4 bs = *(const float4*)(bsum + j0 + tx * 4);
        const int r = (j0 >> 2) + tx;
        #pragma unroll
        for (int i = 0; i < 2; i++) {
            int n = n0 + ty * 2 + i;
            if (n < NN) {
                float gi = acc[i][0] + bs.x;
                float gf = acc[i][1] + bs.y;
                float gg = acc[i][2] + bs.z;
                float go = acc[i][3] + bs.w;
                float cn = sigmf(gf) * c[(size_t)n * RNNW + r] + sigmf(gi) * tanhf(gg);
                float hn = sigmf(go) * tanhf(cn);
                c[(size_t)n * RNNW + r] = cn;
                hout[(size_t)n * RNNW + r] = hn;
                if (t == TT - 1) {
                    out[(size_t)TT * NN * OUTD + (size_t)n * RNNW + r] = hn;
                    out[(size_t)TT * NN * OUTD + (size_t)NN * RNNW + (size_t)n * RNNW + r] = cn;
                }
            }
        }
        // release: make hout visible device-wide, then signal
        __threadfence();
        __syncthreads();
        if (tid == 0) atomicAdd(ctr + t, 1u);
    } else {
        // ================= U' + out-proj (R9 k_U) =========================
        const int ub = bid - 256;
        const int p0 = (ub & 15) * 64;
        const int g  = ub >> 4;
        if (t == TT - 1 && g != 0) return;       // no U' needed after frame 11
        if (tid == 0) {
            while (__hip_atomic_load(ctr + t, __ATOMIC_ACQUIRE,
                                     __HIP_MEMORY_SCOPE_AGENT) < 256u)
                __builtin_amdgcn_s_sleep(8);
        }
        __syncthreads();
        float* sAT = smem;          // [128][64]
        float* sBT = smem + 8192;   // [128][64]
        {
            int pp = tid >> 2, kq = (tid & 3) * 4;
            int p = p0 + pp;
            #pragma unroll
            for (int pass = 0; pass < 8; ++pass) {
                int k0 = pass * 16 + kq;
                float4 v = {0.f, 0.f, 0.f, 0.f};
                if (p < NN) v = *(const float4*)(hout + (size_t)p * RNNW + k0);
                sAT[(k0 + 0) * 64 + pp] = v.x; sAT[(k0 + 1) * 64 + pp] = v.y;
                sAT[(k0 + 2) * 64 + pp] = v.z; sAT[(k0 + 3) * 64 + pp] = v.w;
            }
        }
        if (t < TT - 1) {
            #pragma unroll
            for (int pass = 0; pass < 8; ++pass) {
                int f = pass * 256 + tid;
                int k = f >> 4, e4 = (f & 15) * 4;
                float4 v = *(const float4*)(WsT + (size_t)(g * 128 + k) * 64 + e4);
                *(float4*)(&sBT[k * 64 + e4]) = v;
            }
        }
        __syncthreads();
        if (t < TT - 1) {
            const int tx = tid & 15, ty = tid >> 4;
            float acc[4][4];
            #pragma unroll
            for (int i = 0; i < 4; i++)
                #pragma unroll
                for (int j = 0; j < 4; j++) acc[i][j] = 0.f;
            #pragma unroll 4
            for (int k = 0; k < RNNW; ++k) {
                float4 a4 = *(const float4*)(&sAT[k * 64 + ty * 4]);
                float4 b4 = *(const float4*)(&sBT[k * 64 + tx * 4]);
                const float av[4] = {a4.x, a4.y, a4.z, a4.w};
                const float bv[4] = {b4.x, b4.y, b4.z, b4.w};
                #pragma unroll
                for (int i = 0; i < 4; i++)
                    #pragma unroll
                    for (int j = 0; j < 4; j++) acc[i][j] += av[i] * bv[j];
            }
            #pragma unroll
            for (int i = 0; i < 4; i++) {
                int p = p0 + ty * 4 + i;
                if (p < NN) {
                    float4 v = {acc[i][0], acc[i][1], acc[i][2], acc[i][3]};
                    *(float4*)(U + (size_t)p * UCW + g * 64 + tx * 4) = v;
                }
            }
        }
        if (g == 0) {                       // out-proj of frame t (R9 order)
            for (int task = tid; task < 64 * OUTD; task += 256) {
                int pp = task / OUTD, d = task - pp * OUTD;
                int p = p0 + pp;
                if (p < NN) {
                    float s = b_out[d];
                    const float* wr = W_out + d * RNNW;
                    for (int k = 0; k < RNNW; ++k) s += sAT[k * 64 + pp] * wr[k];
                    out[((size_t)t * NN + p) * OUTD + d] = s;
                }
            }
        }
    }
}

extern "C" void kernel_launch(void* const* d_in, const int* in_sizes, int n_in,
                              void* d_out, int out_size, void* d_ws, size_t ws_size,
                              hipStream_t stream) {
    const float* x_in       = (const float*)d_in[0];
    const unsigned int* grd = (const unsigned int*)d_in[1];
    const float* h0         = (const float*)d_in[2];
    const float* c0         = (const float*)d_in[3];
    const float* W_in       = (const float*)d_in[4];
    const float* b_in       = (const float*)d_in[5];
    const float* W_soc      = (const float*)d_in[6];
    const float* b_soc      = (const float*)d_in[7];
    const float* W_ih       = (const float*)d_in[8];
    const float* W_hh       = (const float*)d_in[9];
    const float* b_ih       = (const float*)d_in[10];
    const float* b_hh       = (const float*)d_in[11];
    const float* W_out      = (const float*)d_in[12];
    const float* b_out      = (const float*)d_in[13];
    float* out = (float*)d_out;

    float* hb0  = (float*)d_ws;                  // 128000
    float* hb1  = hb0 + NN * RNNW;               // 128000
    float* c    = hb1 + NN * RNNW;               // 128000
    float* U    = c + NN * RNNW;                 // 1,024,000
    float* A    = U + (size_t)NN * UCW;          // 128,000
    float* WsT  = A + (size_t)NN * RNNW;         // 131,072
    float* WcT  = WsT + 131072;                  // 131,072
    float* bsum = WcT + 131072;                  // 512
    unsigned int* ctr = (unsigned int*)(bsum + 512);   // 12

    hipLaunchKernelGGL(k_prep, dim3(2027), dim3(256), 0, stream,
                       h0, c0, W_soc, W_ih, W_hh, b_ih, b_hh, hb0, c,
                       WsT, WcT, bsum, ctr);
    hipLaunchKernelGGL(k_U, dim3(16, 16), dim3(256), 0, stream, hb0, WsT, U);
    for (int t = 0; t < TT; ++t) {
        float* hin  = (t & 1) ? hb1 : hb0;
        float* hout = (t & 1) ? hb0 : hb1;
        hipLaunchKernelGGL(k_pool, dim3(NN), dim3(512), 0, stream,
                           grd, x_in, U, W_in, b_in, b_soc, A, t);
        hipLaunchKernelGGL(k_glU, dim3(512), dim3(256), 0, stream,
                           A, hin, hout, c, WcT, bsum, WsT, W_out, b_out,
                           U, out, ctr, t);
    }
}

// Round 15
// 870.217 us; speedup vs baseline: 1.4210x; 1.4210x over previous
//
#include <hip/hip_runtime.h>

// Social-LSTM on MI355X. fp32 I/O. 26 launches.
// Per frame: k_pool (1000 blk, R9-verified ILP-4 ballot-gather -> A)
//            k_cell8 (125 blk x 512, 8 peds/block: pair-packed gates matvec +
//                     LSTM + out-proj + U' for t+1; final h,c folded at t=11).
// U[p][g*64+e] = sum_k h[p][k]*W_soc[e][g*128+k]; te = relu(sum_nz U + b_soc).

#define TT    12
#define NN    1000
#define RNNW  128
#define OUTD  5
#define GROW  16000
#define UCW   1024
#define NCHK  63

__device__ __forceinline__ float sigmf(float x) { return 1.f / (1.f + __expf(-x)); }

// ---- prep: pair-packed weight repacks + h/c init (R6/R13 verified) -------
__global__ void k_prep(const float* __restrict__ h0, const float* __restrict__ c0,
                       const float* __restrict__ W_soc,
                       const float* __restrict__ W_ih, const float* __restrict__ W_hh,
                       float* __restrict__ h, float* __restrict__ c,
                       float* __restrict__ WsT2p, float* __restrict__ WcT2p) {
    int i = blockIdx.x * 256 + threadIdx.x;
    if (i < 131072) {
        int e = i >> 11, gk = i & 2047, g = gk >> 7, k = gk & 127;
        int j = g * 64 + e;
        WsT2p[(k >> 1) * 2048 + j * 2 + (k & 1)] = W_soc[i];
    } else if (i < 196608) {
        int i2 = i - 131072;               // W_ih [512][128]
        int j = i2 >> 7, k = i2 & 127;
        WcT2p[(k >> 1) * 1024 + j * 2 + (k & 1)] = W_ih[i2];
    } else if (i < 262144) {
        int i3 = i - 196608;               // W_hh [512][128]
        int j = i3 >> 7, k = i3 & 127;
        WcT2p[((k >> 1) + 64) * 1024 + j * 2 + (k & 1)] = W_hh[i3];
    } else if (i < 262144 + NN * RNNW) {
        int i4 = i - 262144; h[i4] = h0[i4];
    } else if (i < 262144 + 2 * NN * RNNW) {
        int i5 = i - 262144 - NN * RNNW; c[i5] = c0[i5];
    }
}

// ---- U block-compute for 4 pedestrians (R5/R6 verified) — used by k_U0 ---
__device__ __forceinline__ void compute_U(const float (*sH)[RNNW],
                                          const float* __restrict__ WsT2p,
                                          float* __restrict__ U, int n0, int tid) {
    const int jd = tid;
    float acc0[4] = {0.f, 0.f, 0.f, 0.f};
    float acc1[4] = {0.f, 0.f, 0.f, 0.f};
    for (int k = 0; k < RNNW; k += 4) {
        float4 a[4];
        #pragma unroll
        for (int p = 0; p < 4; ++p) a[p] = *(const float4*)(&sH[p][k]);
        const int r0 = (k >> 1), r1 = (k >> 1) + 1;
        float2 w00 = *(const float2*)(WsT2p + r0 * 2048 + jd * 2);
        float2 w01 = *(const float2*)(WsT2p + r0 * 2048 + (jd + 512) * 2);
        float2 w10 = *(const float2*)(WsT2p + r1 * 2048 + jd * 2);
        float2 w11 = *(const float2*)(WsT2p + r1 * 2048 + (jd + 512) * 2);
        #pragma unroll
        for (int p = 0; p < 4; ++p) {
            acc0[p] += a[p].x * w00.x + a[p].y * w00.y + a[p].z * w10.x + a[p].w * w10.y;
            acc1[p] += a[p].x * w01.x + a[p].y * w01.y + a[p].z * w11.x + a[p].w * w11.y;
        }
    }
    #pragma unroll
    for (int p = 0; p < 4; ++p) {
        U[(size_t)(n0 + p) * UCW + jd]       = acc0[p];
        U[(size_t)(n0 + p) * UCW + jd + 512] = acc1[p];
    }
}

// ---- U for frame 0 (R6/R13 verified) -------------------------------------
__global__ __launch_bounds__(512) void k_U0(const float* __restrict__ h,
                                            const float* __restrict__ WsT2p,
                                            float* __restrict__ U) {
    __shared__ float sH[4][RNNW];
    const int tid = threadIdx.x, n0 = blockIdx.x * 4;
    { int pl = tid >> 7, r = tid & 127; sH[pl][r] = h[(size_t)(n0 + pl) * RNNW + r]; }
    __syncthreads();
    compute_U(sH, WsT2p, U, n0, tid);
}

// ---- pool: 1000 blocks x 512 thr, ILP-4 gather (R9 verified) -------------
__global__ __launch_bounds__(512) void k_pool(const unsigned int* __restrict__ grd,
                                              const float* __restrict__ x_in,
                                              const float* __restrict__ U,
                                              const float* __restrict__ W_in,
                                              const float* __restrict__ b_in,
                                              const float* __restrict__ b_soc,
                                              float* __restrict__ A, int t) {
    const int n = blockIdx.x;
    const int tid = threadIdx.x;
    const int lane = tid & 63, wv = tid >> 6;
    const unsigned int* gp = grd + ((size_t)t * NN + n) * (size_t)GROW;
    float ac0 = 0.f, ac1 = 0.f, ac2 = 0.f, ac3 = 0.f;
    for (int it = 0; it < 8; ++it) {
        int cc = it * 8 + wv;
        if (cc >= NCHK) break;
        int f0 = cc * 256 + lane * 4;
        uint4 v = {0u, 0u, 0u, 0u};
        if (f0 < GROW) v = *(const uint4*)(gp + f0);
        unsigned long long m0 = __ballot(v.x != 0u);
        unsigned long long m1 = __ballot(v.y != 0u);
        unsigned long long m2 = __ballot(v.z != 0u);
        unsigned long long m3 = __ballot(v.w != 0u);
        const int base = cc * 256;
        while (m0 | m1 | m2 | m3) {
            float u0 = 0.f, u1 = 0.f, u2 = 0.f, u3 = 0.f;
            if (m0) { int b = __builtin_ctzll(m0); m0 &= m0 - 1;
                      int f = base + b * 4 + 0;
                      u0 = U[(size_t)(f >> 4) * UCW + (f & 15) * 64 + lane]; }
            if (m1) { int b = __builtin_ctzll(m1); m1 &= m1 - 1;
                      int f = base + b * 4 + 1;
                      u1 = U[(size_t)(f >> 4) * UCW + (f & 15) * 64 + lane]; }
            if (m2) { int b = __builtin_ctzll(m2); m2 &= m2 - 1;
                      int f = base + b * 4 + 2;
                      u2 = U[(size_t)(f >> 4) * UCW + (f & 15) * 64 + lane]; }
            if (m3) { int b = __builtin_ctzll(m3); m3 &= m3 - 1;
                      int f = base + b * 4 + 3;
                      u3 = U[(size_t)(f >> 4) * UCW + (f & 15) * 64 + lane]; }
            ac0 += u0; ac1 += u1; ac2 += u2; ac3 += u3;
        }
    }
    __shared__ float sAcc[8][64];
    sAcc[wv][lane] = (ac0 + ac1) + (ac2 + ac3);
    __syncthreads();
    if (tid < 64) {
        float s = 0.f;
        #pragma unroll
        for (int w = 0; w < 8; w++) s += sAcc[w][tid];
        float te = fmaxf(s + b_soc[tid], 0.f);
        float x0 = x_in[((size_t)t * NN + n) * 2 + 0];
        float x1 = x_in[((size_t)t * NN + n) * 2 + 1];
        float ie = fmaxf(W_in[tid * 2 + 0] * x0 + W_in[tid * 2 + 1] * x1 + b_in[tid], 0.f);
        A[(size_t)n * RNNW + tid]      = ie;
        A[(size_t)n * RNNW + 64 + tid] = te;
    }
}

// ---- cell8: gates + LSTM + out-proj + U'(t+1). Block owns 8 peds. --------
// R6/R13 verified math, ped dimension x2; 125 blocks halve W re-stream.
__global__ __launch_bounds__(512) void k_cell8(const float* __restrict__ A,
                                               float* __restrict__ h, float* __restrict__ c,
                                               const float* __restrict__ WcT2p,
                                               const float* __restrict__ WsT2p,
                                               const float* __restrict__ b_ih,
                                               const float* __restrict__ b_hh,
                                               const float* __restrict__ W_out,
                                               const float* __restrict__ b_out,
                                               float* __restrict__ U,
                                               float* __restrict__ out, int t, int doU) {
    __shared__ float sA[8][RNNW], sH[8][RNNW], sC[8][RNNW];
    __shared__ float sG[8][512];
    __shared__ float sRed[8][2][OUTD];
    const int tid = threadIdx.x;
    const int lane = tid & 63;
    const int n0 = blockIdx.x * 8;
    #pragma unroll
    for (int q = 0; q < 2; ++q) {
        int idx = q * 512 + tid;
        int pl = idx >> 7, r = idx & 127;
        sA[pl][r] = A[(size_t)(n0 + pl) * RNNW + r];
        sH[pl][r] = h[(size_t)(n0 + pl) * RNNW + r];
        sC[pl][r] = c[(size_t)(n0 + pl) * RNNW + r];
    }
    __syncthreads();
    // ---- gates: thread (jh, ph) -> gates {jh, jh+256} x peds {4ph..4ph+3}
    {
        const int jh = tid & 255, ph = tid >> 8;
        const int pb = 4 * ph;
        float gA0 = 0.f, gA1 = 0.f, gB0 = 0.f, gB1 = 0.f;
        float gC0 = 0.f, gC1 = 0.f, gD0 = 0.f, gD1 = 0.f;
        #pragma unroll 4
        for (int k = 0; k < 128; k += 4) {          // [ie|te] part
            float4 aA = *(const float4*)(&sA[pb + 0][k]);
            float4 aB = *(const float4*)(&sA[pb + 1][k]);
            float4 aC = *(const float4*)(&sA[pb + 2][k]);
            float4 aD = *(const float4*)(&sA[pb + 3][k]);
            const int r0 = (k >> 1), r1 = (k >> 1) + 1;
            float2 w00 = *(const float2*)(WcT2p + r0 * 1024 + jh * 2);
            float2 w01 = *(const float2*)(WcT2p + r0 * 1024 + (jh + 256) * 2);
            float2 w10 = *(const float2*)(WcT2p + r1 * 1024 + jh * 2);
            float2 w11 = *(const float2*)(WcT2p + r1 * 1024 + (jh + 256) * 2);
            gA0 += aA.x * w00.x + aA.y * w00.y + aA.z * w10.x + aA.w * w10.y;
            gA1 += aA.x * w01.x + aA.y * w01.y + aA.z * w11.x + aA.w * w11.y;
            gB0 += aB.x * w00.x + aB.y * w00.y + aB.z * w10.x + aB.w * w10.y;
            gB1 += aB.x * w01.x + aB.y * w01.y + aB.z * w11.x + aB.w * w11.y;
            gC0 += aC.x * w00.x + aC.y * w00.y + aC.z * w10.x + aC.w * w10.y;
            gC1 += aC.x * w01.x + aC.y * w01.y + aC.z * w11.x + aC.w * w11.y;
            gD0 += aD.x * w00.x + aD.y * w00.y + aD.z * w10.x + aD.w * w10.y;
            gD1 += aD.x * w01.x + aD.y * w01.y + aD.z * w11.x + aD.w * w11.y;
        }
        #pragma unroll 4
        for (int k = 0; k < 128; k += 4) {          // h part (repack rows 64+)
            float4 aA = *(const float4*)(&sH[pb + 0][k]);
            float4 aB = *(const float4*)(&sH[pb + 1][k]);
            float4 aC = *(const float4*)(&sH[pb + 2][k]);
            float4 aD = *(const float4*)(&sH[pb + 3][k]);
            const int r0 = 64 + (k >> 1), r1 = 64 + (k >> 1) + 1;
            float2 w00 = *(const float2*)(WcT2p + r0 * 1024 + jh * 2);
            float2 w01 = *(const float2*)(WcT2p + r0 * 1024 + (jh + 256) * 2);
            float2 w10 = *(const float2*)(WcT2p + r1 * 1024 + jh * 2);
            float2 w11 = *(const float2*)(WcT2p + r1 * 1024 + (jh + 256) * 2);
            gA0 += aA.x * w00.x + aA.y * w00.y + aA.z * w10.x + aA.w * w10.y;
            gA1 += aA.x * w01.x + aA.y * w01.y + aA.z * w11.x + aA.w * w11.y;
            gB0 += aB.x * w00.x + aB.y * w00.y + aB.z * w10.x + aB.w * w10.y;
            gB1 += aB.x * w01.x + aB.y * w01.y + aB.z * w11.x + aB.w * w11.y;
            gC0 += aC.x * w00.x + aC.y * w00.y + aC.z * w10.x + aC.w * w10.y;
            gC1 += aC.x * w01.x + aC.y * w01.y + aC.z * w11.x + aC.w * w11.y;
            gD0 += aD.x * w00.x + aD.y * w00.y + aD.z * w10.x + aD.w * w10.y;
            gD1 += aD.x * w01.x + aD.y * w01.y + aD.z * w11.x + aD.w * w11.y;
        }
        float bias0 = b_ih[jh] + b_hh[jh];
        float bias1 = b_ih[jh + 256] + b_hh[jh + 256];
        sG[pb + 0][jh]       = gA0 + bias0;  sG[pb + 0][jh + 256] = gA1 + bias1;
        sG[pb + 1][jh]       = gB0 + bias0;  sG[pb + 1][jh + 256] = gB1 + bias1;
        sG[pb + 2][jh]       = gC0 + bias0;  sG[pb + 2][jh + 256] = gC1 + bias1;
        sG[pb + 3][jh]       = gD0 + bias0;  sG[pb + 3][jh + 256] = gD1 + bias1;
    }
    __syncthreads();
    // ---- LSTM elementwise (2 passes) ----
    #pragma unroll
    for (int q = 0; q < 2; ++q) {
        int idx = q * 512 + tid;
        int pl = idx >> 7, r = idx & 127;
        float gi = sG[pl][r], gf = sG[pl][128 + r];
        float gg = sG[pl][256 + r], go = sG[pl][384 + r];
        float cn = sigmf(gf) * sC[pl][r] + sigmf(gi) * tanhf(gg);
        float hn = sigmf(go) * tanhf(cn);
        sC[pl][r] = cn;
        sH[pl][r] = hn;
        c[(size_t)(n0 + pl) * RNNW + r] = cn;
        h[(size_t)(n0 + pl) * RNNW + r] = hn;
        if (t == TT - 1) {
            out[(size_t)TT * NN * OUTD + (size_t)(n0 + pl) * RNNW + r] = hn;
            out[(size_t)TT * NN * OUTD + (size_t)NN * RNNW + (size_t)(n0 + pl) * RNNW + r] = cn;
        }
    }
    __syncthreads();
    // ---- out projection (R6-verified shuffle reduce, 2 passes) ----
    #pragma unroll
    for (int q = 0; q < 2; ++q) {
        int pl = q * 4 + (tid >> 7), p128 = tid & 127, wh = (tid >> 6) & 1;
        float v = sH[pl][p128];
        #pragma unroll
        for (int d = 0; d < OUTD; ++d) {
            float pr = v * W_out[d * RNNW + p128];
            #pragma unroll
            for (int off = 32; off > 0; off >>= 1) pr += __shfl_down(pr, off);
            if (lane == 0) sRed[pl][wh][d] = pr;
        }
        __syncthreads();
    }
    if (tid < 8 * OUTD) {
        int pl = tid / OUTD, d = tid % OUTD;
        out[((size_t)t * NN + n0 + pl) * OUTD + d] =
            sRed[pl][0][d] + sRed[pl][1][d] + b_out[d];
    }
    // ---- U' for t+1: 8 peds, pair-packed (same per-j order as compute_U) -
    if (doU) {
        const int jd = tid;
        float a0[8], a1[8];
        #pragma unroll
        for (int p = 0; p < 8; ++p) { a0[p] = 0.f; a1[p] = 0.f; }
        for (int k = 0; k < RNNW; k += 4) {
            float4 hv[8];
            #pragma unroll
            for (int p = 0; p < 8; ++p) hv[p] = *(const float4*)(&sH[p][k]);
            const int r0 = (k >> 1), r1 = (k >> 1) + 1;
            float2 w00 = *(const float2*)(WsT2p + r0 * 2048 + jd * 2);
            float2 w01 = *(const float2*)(WsT2p + r0 * 2048 + (jd + 512) * 2);
            float2 w10 = *(const float2*)(WsT2p + r1 * 2048 + jd * 2);
            float2 w11 = *(const float2*)(WsT2p + r1 * 2048 + (jd + 512) * 2);
            #pragma unroll
            for (int p = 0; p < 8; ++p) {
                a0[p] += hv[p].x * w00.x + hv[p].y * w00.y + hv[p].z * w10.x + hv[p].w * w10.y;
                a1[p] += hv[p].x * w01.x + hv[p].y * w01.y + hv[p].z * w11.x + hv[p].w * w11.y;
            }
        }
        #pragma unroll
        for (int p = 0; p < 8; ++p) {
            U[(size_t)(n0 + p) * UCW + jd]       = a0[p];
            U[(size_t)(n0 + p) * UCW + jd + 512] = a1[p];
        }
    }
}

extern "C" void kernel_launch(void* const* d_in, const int* in_sizes, int n_in,
                              void* d_out, int out_size, void* d_ws, size_t ws_size,
                              hipStream_t stream) {
    const float* x_in       = (const float*)d_in[0];
    const unsigned int* grd = (const unsigned int*)d_in[1];
    const float* h0         = (const float*)d_in[2];
    const float* c0         = (const float*)d_in[3];
    const float* W_in       = (const float*)d_in[4];
    const float* b_in       = (const float*)d_in[5];
    const float* W_soc      = (const float*)d_in[6];
    const float* b_soc      = (const float*)d_in[7];
    const float* W_ih       = (const float*)d_in[8];
    const float* W_hh       = (const float*)d_in[9];
    const float* b_ih       = (const float*)d_in[10];
    const float* b_hh       = (const float*)d_in[11];
    const float* W_out      = (const float*)d_in[12];
    const float* b_out      = (const float*)d_in[13];
    float* out = (float*)d_out;

    float* h      = (float*)d_ws;                 // 128000
    float* c      = h + NN * RNNW;                // 128000
    float* U      = c + NN * RNNW;                // 1,024,000
    float* A      = U + (size_t)NN * UCW;         // 128,000
    float* WsT2p  = A + (size_t)NN * RNNW;        // 131,072
    float* WcT2p  = WsT2p + 131072;               // 131,072   (~6.1 MB)

    hipLaunchKernelGGL(k_prep, dim3(2024), dim3(256), 0, stream,
                       h0, c0, W_soc, W_ih, W_hh, h, c, WsT2p, WcT2p);
    hipLaunchKernelGGL(k_U0, dim3(250), dim3(512), 0, stream, h, WsT2p, U);
    for (int t = 0; t < TT; ++t) {
        hipLaunchKernelGGL(k_pool, dim3(NN), dim3(512), 0, stream,
                           grd, x_in, U, W_in, b_in, b_soc, A, t);
        hipLaunchKernelGGL(k_cell8, dim3(125), dim3(512), 0, stream,
                           A, h, c, WcT2p, WsT2p, b_ih, b_hh, W_out, b_out,
                           U, out, t, (t < TT - 1) ? 1 : 0);
    }
}

// Round 16
// 641.831 us; speedup vs baseline: 1.9267x; 1.3558x over previous
//
#include <hip/hip_runtime.h>

// Social-LSTM on MI355X. fp32 I/O. 38 launches. (R9 structure — measured best.)
// Per frame: k_pool (1000 blk, ILP-4 ballot-gather) -> k_gl (256 blk,
// j2-permuted gates GEMM + in-register LSTM, h double-buffered) -> k_U
// (256 blk tiled U-GEMM for frame t+1, + out-proj of frame t from staged h^T).
// U[p][g*64+e] = sum_k h[p][k]*W_soc[e][g*128+k]; te = relu(sum_nz U + b_soc).

#define TT    12
#define NN    1000
#define RNNW  128
#define OUTD  5
#define GROW  16000     // N*G floats per (t,n) grid row
#define UCW   1024
#define NCHK  63        // ceil(16000/256)

__device__ __forceinline__ float sigmf(float x) { return 1.f / (1.f + __expf(-x)); }

// ---- prep: WsT (k-major W_soc), WcT (k-major, j2=r*4+gate permuted),
// bsum[j2]=b_ih+b_hh, h/c init ---------------------------------------------
__global__ void k_prep(const float* __restrict__ h0, const float* __restrict__ c0,
                       const float* __restrict__ W_soc,
                       const float* __restrict__ W_ih, const float* __restrict__ W_hh,
                       const float* __restrict__ b_ih, const float* __restrict__ b_hh,
                       float* __restrict__ h, float* __restrict__ c,
                       float* __restrict__ WsT, float* __restrict__ WcT,
                       float* __restrict__ bsum) {
    int i = blockIdx.x * 256 + threadIdx.x;
    if (i < 131072) {                       // WsT[gk][e] = W_soc[e][gk]
        int e = i >> 11, gk = i & 2047;
        WsT[gk * 64 + e] = W_soc[i];
    } else if (i < 196608) {                // W_ih [512][128] -> WcT[k][j2]
        int i2 = i - 131072;
        int j = i2 >> 7, k = i2 & 127;
        int j2 = (j & 127) * 4 + (j >> 7);
        WcT[k * 512 + j2] = W_ih[i2];
    } else if (i < 262144) {                // W_hh -> WcT[128+k][j2]
        int i3 = i - 196608;
        int j = i3 >> 7, k = i3 & 127;
        int j2 = (j & 127) * 4 + (j >> 7);
        WcT[(128 + k) * 512 + j2] = W_hh[i3];
    } else if (i < 262656) {                // bsum[j2]
        int j = i - 262144;
        int j2 = (j & 127) * 4 + (j >> 7);
        bsum[j2] = b_ih[j] + b_hh[j];
    } else if (i < 262656 + NN * RNNW) {
        int i4 = i - 262656; h[i4] = h0[i4];
    } else if (i < 262656 + 2 * NN * RNNW) {
        int i5 = i - 262656 - NN * RNNW; c[i5] = c0[i5];
    }
}

// ---- k_U: U for frame t+1 (R3-verified tile) + out-proj of frame t -------
__global__ __launch_bounds__(256) void k_U(const float* __restrict__ h,
                                           const float* __restrict__ WsT,
                                           const float* __restrict__ W_out,
                                           const float* __restrict__ b_out,
                                           float* __restrict__ U,
                                           float* __restrict__ out, int t) {
    __shared__ float sAT[RNNW][64];   // h^T tile (stays valid after GEMM)
    __shared__ float sBT[RNNW][64];
    const int tid = threadIdx.x;
    const int p0 = blockIdx.x * 64;
    const int g  = blockIdx.y;
    {   // stage sAT: transpose h[p0+pp][k] -> sAT[k][pp]
        int pp = tid >> 2, kq = (tid & 3) * 4;
        int p = p0 + pp;
        #pragma unroll
        for (int pass = 0; pass < 8; ++pass) {
            int k0 = pass * 16 + kq;
            float4 v = {0.f, 0.f, 0.f, 0.f};
            if (p < NN) v = *(const float4*)(h + (size_t)p * RNNW + k0);
            sAT[k0 + 0][pp] = v.x; sAT[k0 + 1][pp] = v.y;
            sAT[k0 + 2][pp] = v.z; sAT[k0 + 3][pp] = v.w;
        }
    }
    {   // stage sBT (rows g*128..+127 of WsT)
        #pragma unroll
        for (int pass = 0; pass < 8; ++pass) {
            int f = pass * 256 + tid;
            int k = f >> 4, e4 = (f & 15) * 4;
            float4 v = *(const float4*)(WsT + (size_t)(g * 128 + k) * 64 + e4);
            *(float4*)(&sBT[k][e4]) = v;
        }
    }
    __syncthreads();
    const int tx = tid & 15, ty = tid >> 4;
    float acc[4][4];
    #pragma unroll
    for (int i = 0; i < 4; i++)
        #pragma unroll
        for (int j = 0; j < 4; j++) acc[i][j] = 0.f;
    #pragma unroll 4
    for (int k = 0; k < RNNW; ++k) {
        float4 a4 = *(const float4*)(&sAT[k][ty * 4]);
        float4 b4 = *(const float4*)(&sBT[k][tx * 4]);
        const float av[4] = {a4.x, a4.y, a4.z, a4.w};
        const float bv[4] = {b4.x, b4.y, b4.z, b4.w};
        #pragma unroll
        for (int i = 0; i < 4; i++)
            #pragma unroll
            for (int j = 0; j < 4; j++) acc[i][j] += av[i] * bv[j];
    }
    #pragma unroll
    for (int i = 0; i < 4; i++) {
        int p = p0 + ty * 4 + i;
        if (p < NN) {
            float4 v = {acc[i][0], acc[i][1], acc[i][2], acc[i][3]};
            *(float4*)(U + (size_t)p * UCW + g * 64 + tx * 4) = v;
        }
    }
    // ---- out-proj of frame t from sAT (g==0 blocks) ----------------------
    if (t >= 0 && g == 0) {
        for (int task = tid; task < 64 * OUTD; task += 256) {
            int pp = task / OUTD, d = task - pp * OUTD;
            int p = p0 + pp;
            if (p < NN) {
                float s = b_out[d];
                const float* wr = W_out + d * RNNW;
                for (int k = 0; k < RNNW; ++k) s += sAT[k][pp] * wr[k];
                out[((size_t)t * NN + p) * OUTD + d] = s;
            }
        }
    }
}

// ---- pool: 1000 blocks x 512 thr, ILP-4 gather (R8-verified inner) -------
__global__ __launch_bounds__(512) void k_pool(const unsigned int* __restrict__ grd,
                                              const float* __restrict__ x_in,
                                              const float* __restrict__ U,
                                              const float* __restrict__ W_in,
                                              const float* __restrict__ b_in,
                                              const float* __restrict__ b_soc,
                                              float* __restrict__ A, int t) {
    const int n = blockIdx.x;
    const int tid = threadIdx.x;
    const int lane = tid & 63, wv = tid >> 6;            // 8 waves
    const unsigned int* gp = grd + ((size_t)t * NN + n) * (size_t)GROW;
    float ac0 = 0.f, ac1 = 0.f, ac2 = 0.f, ac3 = 0.f;
    for (int it = 0; it < 8; ++it) {
        int cc = it * 8 + wv;                            // wave-uniform chunk
        if (cc >= NCHK) break;
        int f0 = cc * 256 + lane * 4;
        uint4 v = {0u, 0u, 0u, 0u};
        if (f0 < GROW) v = *(const uint4*)(gp + f0);
        unsigned long long m0 = __ballot(v.x != 0u);
        unsigned long long m1 = __ballot(v.y != 0u);
        unsigned long long m2 = __ballot(v.z != 0u);
        unsigned long long m3 = __ballot(v.w != 0u);
        const int base = cc * 256;
        while (m0 | m1 | m2 | m3) {       // ILP-4: up to 4 loads in flight
            float u0 = 0.f, u1 = 0.f, u2 = 0.f, u3 = 0.f;
            if (m0) { int b = __builtin_ctzll(m0); m0 &= m0 - 1;
                      int f = base + b * 4 + 0;
                      u0 = U[(size_t)(f >> 4) * UCW + (f & 15) * 64 + lane]; }
            if (m1) { int b = __builtin_ctzll(m1); m1 &= m1 - 1;
                      int f = base + b * 4 + 1;
                      u1 = U[(size_t)(f >> 4) * UCW + (f & 15) * 64 + lane]; }
            if (m2) { int b = __builtin_ctzll(m2); m2 &= m2 - 1;
                      int f = base + b * 4 + 2;
                      u2 = U[(size_t)(f >> 4) * UCW + (f & 15) * 64 + lane]; }
            if (m3) { int b = __builtin_ctzll(m3); m3 &= m3 - 1;
                      int f = base + b * 4 + 3;
                      u3 = U[(size_t)(f >> 4) * UCW + (f & 15) * 64 + lane]; }
            ac0 += u0; ac1 += u1; ac2 += u2; ac3 += u3;  // +0.0f exact
        }
    }
    __shared__ float sAcc[8][64];
    sAcc[wv][lane] = (ac0 + ac1) + (ac2 + ac3);
    __syncthreads();
    if (tid < 64) {
        float s = 0.f;
        #pragma unroll
        for (int w = 0; w < 8; w++) s += sAcc[w][tid];
        float te = fmaxf(s + b_soc[tid], 0.f);
        float x0 = x_in[((size_t)t * NN + n) * 2 + 0];
        float x1 = x_in[((size_t)t * NN + n) * 2 + 1];
        float ie = fmaxf(W_in[tid * 2 + 0] * x0 + W_in[tid * 2 + 1] * x1 + b_in[tid], 0.f);
        A[(size_t)n * RNNW + tid]      = ie;
        A[(size_t)n * RNNW + 64 + tid] = te;
    }
}

// ---- k_gl: gates GEMM (j2-permuted, R3-verified tile) + in-register LSTM -
// grid (32, 8): 32 n-tiles x 8 j2-tiles of 64 (= 16 r's x 4 gates). 256 thr.
__global__ __launch_bounds__(256) void k_gl(const float* __restrict__ A,
                                            const float* __restrict__ hin,
                                            float* __restrict__ hout,
                                            float* __restrict__ c,
                                            const float* __restrict__ WcT,
                                            const float* __restrict__ bsum,
                                            float* __restrict__ out, int t) {
    __shared__ float sAT[128][32];
    __shared__ float sBT[128][64];
    const int tid = threadIdx.x;
    const int n0 = blockIdx.x * 32;
    const int j0 = blockIdx.y * 64;
    const int tx = tid & 15, ty = tid >> 4;
    float acc[2][4];
    #pragma unroll
    for (int i = 0; i < 2; i++)
        #pragma unroll
        for (int j = 0; j < 4; j++) acc[i][j] = 0.f;
    for (int kc = 0; kc < 2; ++kc) {
        __syncthreads();
        {   // stage sAT: kc=0 from A=[ie|te], kc=1 from h(t-1)
            int nn = tid >> 3, kq = (tid & 7) * 4;
            int n = n0 + nn;
            const float* src = kc ? (hin + (size_t)n * RNNW) : (A + (size_t)n * RNNW);
            #pragma unroll
            for (int pass = 0; pass < 4; ++pass) {
                int k0 = pass * 32 + kq;
                float4 v = {0.f, 0.f, 0.f, 0.f};
                if (n < NN) v = *(const float4*)(src + k0);
                sAT[k0 + 0][nn] = v.x; sAT[k0 + 1][nn] = v.y;
                sAT[k0 + 2][nn] = v.z; sAT[k0 + 3][nn] = v.w;
            }
        }
        {   // stage sBT: WcT rows kc*128..+127, cols j0..j0+63
            #pragma unroll
            for (int pass = 0; pass < 8; ++pass) {
                int f = pass * 256 + tid;
                int k = f >> 4, e4 = (f & 15) * 4;
                float4 v = *(const float4*)(WcT + (size_t)(kc * 128 + k) * 512 + j0 + e4);
                *(float4*)(&sBT[k][e4]) = v;
            }
        }
        __syncthreads();
        #pragma unroll 4
        for (int k = 0; k < 128; ++k) {
            float2 a2 = *(const float2*)(&sAT[k][ty * 2]);
            float4 b4 = *(const float4*)(&sBT[k][tx * 4]);
            const float av[2] = {a2.x, a2.y};
            const float bv[4] = {b4.x, b4.y, b4.z, b4.w};
            #pragma unroll
            for (int i = 0; i < 2; i++)
                #pragma unroll
                for (int j = 0; j < 4; j++) acc[i][j] += av[i] * bv[j];
        }
    }
    // ---- epilogue: acc[i] = {i,f,g,o} gates of (n, r) -> LSTM ------------
    float4 bs = *(const float4*)(bsum + j0 + tx * 4);
    const int r = (j0 >> 2) + tx;
    #pragma unroll
    for (int i = 0; i < 2; i++) {
        int n = n0 + ty * 2 + i;
        if (n < NN) {
            float gi = acc[i][0] + bs.x;
            float gf = acc[i][1] + bs.y;
            float gg = acc[i][2] + bs.z;
            float go = acc[i][3] + bs.w;
            float cn = sigmf(gf) * c[(size_t)n * RNNW + r] + sigmf(gi) * tanhf(gg);
            float hn = sigmf(go) * tanhf(cn);
            c[(size_t)n * RNNW + r] = cn;
            hout[(size_t)n * RNNW + r] = hn;
            if (t == TT - 1) {   // final h,c tail of d_out
                out[(size_t)TT * NN * OUTD + (size_t)n * RNNW + r] = hn;
                out[(size_t)TT * NN * OUTD + (size_t)NN * RNNW + (size_t)n * RNNW + r] = cn;
            }
        }
    }
}

// ---- tail: out-proj of frame 11 ------------------------------------------
__global__ __launch_bounds__(256) void k_tail(const float* __restrict__ h,
                                              const float* __restrict__ W_out,
                                              const float* __restrict__ b_out,
                                              float* __restrict__ out) {
    int task = blockIdx.x * 256 + threadIdx.x;       // 5000 tasks
    if (task < NN * OUTD) {
        int p = task / OUTD, d = task - p * OUTD;
        float s = b_out[d];
        const float* wr = W_out + d * RNNW;
        const float* hp = h + (size_t)p * RNNW;
        for (int k = 0; k < RNNW; ++k) s += hp[k] * wr[k];
        out[((size_t)(TT - 1) * NN + p) * OUTD + d] = s;
    }
}

extern "C" void kernel_launch(void* const* d_in, const int* in_sizes, int n_in,
                              void* d_out, int out_size, void* d_ws, size_t ws_size,
                              hipStream_t stream) {
    const float* x_in       = (const float*)d_in[0];
    const unsigned int* grd = (const unsigned int*)d_in[1];
    const float* h0         = (const float*)d_in[2];
    const float* c0         = (const float*)d_in[3];
    const float* W_in       = (const float*)d_in[4];
    const float* b_in       = (const float*)d_in[5];
    const float* W_soc      = (const float*)d_in[6];
    const float* b_soc      = (const float*)d_in[7];
    const float* W_ih       = (const float*)d_in[8];
    const float* W_hh       = (const float*)d_in[9];
    const float* b_ih       = (const float*)d_in[10];
    const float* b_hh       = (const float*)d_in[11];
    const float* W_out      = (const float*)d_in[12];
    const float* b_out      = (const float*)d_in[13];
    float* out = (float*)d_out;

    float* hb0  = (float*)d_ws;                  // 128000
    float* hb1  = hb0 + NN * RNNW;               // 128000
    float* c    = hb1 + NN * RNNW;               // 128000
    float* U    = c + NN * RNNW;                 // 1,024,000
    float* A    = U + (size_t)NN * UCW;          // 128,000
    float* WsT  = A + (size_t)NN * RNNW;         // 131,072
    float* WcT  = WsT + 131072;                  // 131,072
    float* bsum = WcT + 131072;                  // 512

    hipLaunchKernelGGL(k_prep, dim3(2026), dim3(256), 0, stream,
                       h0, c0, W_soc, W_ih, W_hh, b_ih, b_hh, hb0, c, WsT, WcT, bsum);
    // U for frame 0 (no out-proj: t=-1)
    hipLaunchKernelGGL(k_U, dim3(16, 16), dim3(256), 0, stream,
                       hb0, WsT, W_out, b_out, U, out, -1);
    for (int t = 0; t < TT; ++t) {
        float* hin  = (t & 1) ? hb1 : hb0;
        float* hout = (t & 1) ? hb0 : hb1;
        hipLaunchKernelGGL(k_pool, dim3(NN), dim3(512), 0, stream,
                           grd, x_in, U, W_in, b_in, b_soc, A, t);
        hipLaunchKernelGGL(k_gl, dim3(32, 8), dim3(256), 0, stream,
                           A, hin, hout, c, WcT, bsum, out, t);
        if (t < TT - 1) {   // U for frame t+1 + out-proj of frame t
            hipLaunchKernelGGL(k_U, dim3(16, 16), dim3(256), 0, stream,
                               hout, WsT, W_out, b_out, U, out, t);
        }
    }
    // out-proj of frame 11 (h after frame 11 = hb0 since 11 is odd -> hout=hb0)
    hipLaunchKernelGGL(k_tail, dim3(20), dim3(256), 0, stream,
                       hb0, W_out, b_out, out);
}